// Round 8
// baseline (25915.820 us; speedup 1.0000x reference)
//
#include <hip/hip_runtime.h>
#include <math.h>

// Problem constants
#define BB   256    // batch
#define TT   1024   // timesteps
#define HH   512    // hidden
#define NWG  256    // 1 WG per CU
#define NTHR 512    // 8 waves
#define SLOT (HH*BB)   // u32 elements per h slot (packed hi|lo, layout [k>>2][b][k&3])
#define PADX 20     // xch row stride (floats): conflict-free, 16B-aligned

typedef _Float16 f16;
typedef _Float16 f16x8 __attribute__((ext_vector_type(8)));
typedef float    f32x4 __attribute__((ext_vector_type(4)));
typedef unsigned int u32;
typedef u32 u32x4 __attribute__((ext_vector_type(4)));

__device__ __forceinline__ f32x4 mf(f16x8 a, f16x8 b, f32x4 c){
  return __builtin_amdgcn_mfma_f32_16x16x32_f16(a, b, c, 0, 0, 0);
}

__device__ __forceinline__ float fast_sigmoid(float v){
  float e = __expf(-v);
  return __builtin_amdgcn_rcpf(1.0f + e);
}
__device__ __forceinline__ float fast_tanh(float v){
  float a = fabsf(v);
  float e = __expf(-2.0f * a);
  float r = (1.0f - e) * __builtin_amdgcn_rcpf(1.0f + e);
  return copysignf(r, v);
}

// pack fp32 -> (hi f16 | lo f16<<16), lo pre-scaled by 2^11
__device__ __forceinline__ u32 pack_hl(float hv){
  const f16 hh = (f16)hv;
  const f16 ll = (f16)((hv - (float)hh) * 2048.0f);
  union {f16 f; unsigned short u;} ch, cl; ch.f = hh; cl.f = ll;
  return (u32)ch.u | ((u32)cl.u << 16);
}
__device__ __forceinline__ float unpack_f(u32 v){
  union {unsigned short u; f16 f;} h, l;
  h.u = (unsigned short)(v & 0xffffu);
  l.u = (unsigned short)(v >> 16);
  return (float)h.f + (float)l.f * (1.0f/2048.0f);
}
// device-coherent write-through stores (land at L3; L2 never dirty for these)
__device__ __forceinline__ void st_u32_wt(u32* p, u32 v){
  __hip_atomic_store(p, v, __ATOMIC_RELAXED, __HIP_MEMORY_SCOPE_AGENT);
}
__device__ __forceinline__ void st_f32_wt(float* p, float v){
  __hip_atomic_store(p, v, __ATOMIC_RELAXED, __HIP_MEMORY_SCOPE_AGENT);
}

// build hi/lo f16x8 fragments from interleaved layout: two dwordx4 loads
__device__ __forceinline__ void build_frag4(const u32* pk, f16x8& fh, f16x8& fl){
  union {u32x4 v4; u32 v[4];} a, b;
  a.v4 = *(const u32x4*)pk;
  b.v4 = *(const u32x4*)(pk + 1024);
  union {u32 u[4]; f16x8 f;} H, L;
  H.u[0] = __builtin_amdgcn_perm(a.v[1], a.v[0], 0x05040100u);
  H.u[1] = __builtin_amdgcn_perm(a.v[3], a.v[2], 0x05040100u);
  H.u[2] = __builtin_amdgcn_perm(b.v[1], b.v[0], 0x05040100u);
  H.u[3] = __builtin_amdgcn_perm(b.v[3], b.v[2], 0x05040100u);
  L.u[0] = __builtin_amdgcn_perm(a.v[1], a.v[0], 0x07060302u);
  L.u[1] = __builtin_amdgcn_perm(a.v[3], a.v[2], 0x07060302u);
  L.u[2] = __builtin_amdgcn_perm(b.v[1], b.v[0], 0x07060302u);
  L.u[3] = __builtin_amdgcn_perm(b.v[3], b.v[2], 0x07060302u);
  fh = H.f; fl = L.f;
}

// ---------- steady-state DOMAIN barrier (128 WGs per batch half) ----------
// NO agent-release fence (no buffer_wbl2): all cross-visible stores are WT;
// the pre-arrival __syncthreads drains them (vmcnt0). Workgroup-release keeps
// compiler ordering. Arrival: 16 counters -> master -> 16 flag replicas.
// Every WAVE polls its replica independently, then per-wave agent-acquire
// (buffer_inv) -- no second __syncthreads.
__device__ __forceinline__ void gridbar_d(unsigned* barb, unsigned ph){
  __syncthreads();                                   // waits vmcnt(0): WT stores at L3
  const unsigned g = (blockIdx.x >> 1) & 15u;
  if (threadIdx.x == 0){
    __builtin_amdgcn_fence(__ATOMIC_RELEASE, "workgroup");   // ordering only, no wbl2
    unsigned old = __hip_atomic_fetch_add(&barb[g*16], 1u, __ATOMIC_RELAXED, __HIP_MEMORY_SCOPE_AGENT);
    if (old + 1u == 8u*ph){
      unsigned om = __hip_atomic_fetch_add(&barb[256], 1u, __ATOMIC_RELAXED, __HIP_MEMORY_SCOPE_AGENT);
      if (om + 1u == 16u*ph){
        #pragma unroll
        for (int r = 0; r < 16; ++r)
          __hip_atomic_store(&barb[320 + r*16], ph, __ATOMIC_RELAXED, __HIP_MEMORY_SCOPE_AGENT);
      }
    }
  }
  if ((threadIdx.x & 63) == 0){                      // each wave's lane0 polls
    while (__hip_atomic_load(&barb[320 + g*16], __ATOMIC_RELAXED, __HIP_MEMORY_SCOPE_AGENT) < ph){
      __builtin_amdgcn_s_sleep(1);
    }
  }
  __builtin_amdgcn_fence(__ATOMIC_ACQUIRE, "agent"); // per-wave buffer_inv
}

// GLOBAL fenced barrier (init only): all 256 WGs.
__device__ __forceinline__ void gridbar_g(unsigned* barb, unsigned ph){
  __syncthreads();
  if (threadIdx.x == 0){
    __builtin_amdgcn_fence(__ATOMIC_RELEASE, "agent");
    const unsigned g = blockIdx.x & 31u;
    unsigned old = __hip_atomic_fetch_add(&barb[g*16], 1u, __ATOMIC_RELAXED, __HIP_MEMORY_SCOPE_AGENT);
    if (old + 1u == 8u*ph){
      unsigned om = __hip_atomic_fetch_add(&barb[512], 1u, __ATOMIC_RELAXED, __HIP_MEMORY_SCOPE_AGENT);
      if (om + 1u == 32u*ph){
        #pragma unroll
        for (int r = 0; r < 32; ++r)
          __hip_atomic_store(&barb[544 + r*16], ph, __ATOMIC_RELAXED, __HIP_MEMORY_SCOPE_AGENT);
      }
    }
    while (__hip_atomic_load(&barb[544 + g*16], __ATOMIC_RELAXED, __HIP_MEMORY_SCOPE_AGENT) < ph){
      __builtin_amdgcn_s_sleep(2);
    }
    __builtin_amdgcn_fence(__ATOMIC_ACQUIRE, "agent");
  }
  __syncthreads();
}

// ws layout (bytes): [0,16K) barriers (dom0 @0, dom1 @4K, global @8K),
// [16K, 16K+1M) xT fp32 [T][B], then 2 packed-u32 planes of 2 slots: h1p, h2p.
__global__ __launch_bounds__(NTHR, 2) void lstm_mfma(
    const float* __restrict__ x,      const float* __restrict__ W_ih1,
    const float* __restrict__ W_hh1,  const float* __restrict__ b1,
    const float* __restrict__ W_ih2,  const float* __restrict__ W_hh2,
    const float* __restrict__ b2,     const float* __restrict__ W_lin,
    const float* __restrict__ b_lin,  float* __restrict__ out,
    char* __restrict__ wsb)
{
  // A fragments in exact MFMA layout: index [chunk*64 + lane], 16B each.
  __shared__ f16x8 A2hi[2048], A2lo[2048], A1hi[1024], A1lo[1024]; // 96 KB
  __shared__ float xch[8][16*PADX];  // per-wave gate-exchange scratch (padded)
  __shared__ float wlin_s[512];
  __shared__ float outpart[2][8];

  unsigned* bar = (unsigned*)wsb;
  float* xT = (float*)(wsb + 16384);
  u32* h1p = (u32*)(wsb + 16384 + 1048576);  // 2 slots
  u32* h2p = h1p + 2*SLOT;                    // 2 slots

  const int w   = blockIdx.x,  tid = threadIdx.x;
  const int l   = tid & 63,    wv  = tid >> 6;       // lane, wave
  const int quad = l >> 4,     lc  = l & 15;
  const int p = w >> 1, cb = w & 1;                  // row-group, batch half (cb == XCD parity)
  const int j0 = 4*p;                                // this WG's 4 hidden columns
  const int bcol = cb*128 + wv*16 + lc;              // this lane's batch column
  const int jq = j0 + quad;                          // this lane's j (post-exchange)
  const int b_out = cb*128 + p;                      // out row handled by this WG (intra-half)
  unsigned* dbar = bar + cb*1024;                    // domain barrier base
  unsigned* gbar = bar + 2048;                       // global barrier base

  // ---------------- init: weight split into LDS frag-order ----------------
  {
    const int g_ = lc >> 2, jj_ = lc & 3;            // A-row m = lc -> (gate, jj)
    const int wrow = g_*HH + j0 + jj_;
    const float* rowI  = W_ih2 + (size_t)wrow*HH;
    const float* rowH2 = W_hh2 + (size_t)wrow*HH;
    const float* rowH1 = W_hh1 + (size_t)wrow*HH;
    for (int c = wv; c < 32; c += 8){
      const int kb = c*32 + quad*8;
      union {f16x8 v; f16 e[8];} hi8, lo8;
      #pragma unroll
      for (int i = 0; i < 8; ++i){
        const int k = kb + i;
        const float wval = (k < HH) ? rowI[k] : rowH2[k - HH];
        const f16 h_ = (f16)wval;
        hi8.e[i] = h_;
        lo8.e[i] = (f16)((wval - (float)h_) * 2048.0f);
      }
      A2hi[c*64 + l] = hi8.v;
      A2lo[c*64 + l] = lo8.v;
    }
    for (int c = wv; c < 16; c += 8){
      const int kb = c*32 + quad*8;
      union {f16x8 v; f16 e[8];} hi8, lo8;
      #pragma unroll
      for (int i = 0; i < 8; ++i){
        const float wval = rowH1[kb + i];
        const f16 h_ = (f16)wval;
        hi8.e[i] = h_;
        lo8.e[i] = (f16)((wval - (float)h_) * 2048.0f);
      }
      A1hi[c*64 + l] = hi8.v;
      A1lo[c*64 + l] = lo8.v;
    }
  }
  // per-lane scalars (j = jq)
  float wih1r[4], b1r[4], b2r[4];
  #pragma unroll
  for (int g = 0; g < 4; ++g){
    wih1r[g] = W_ih1[g*HH + jq];
    b1r[g]   = b1[g*HH + jq];
    b2r[g]   = b2[g*HH + jq];
  }
  const float blin = b_lin[0];
  wlin_s[tid] = W_lin[tid];

  // x transpose -> xT[t][b] (plain stores; made visible by the fenced global barrier)
  {
    const int gid = w*NTHR + tid;
    #pragma unroll
    for (int i2 = 0; i2 < 2; ++i2){
      const int idx = gid + i2*131072;
      const int bb2 = idx >> 10, tt2 = idx & (TT-1);
      xT[(size_t)tt2*BB + bb2] = x[idx];
    }
  }
  // zero h2 slot 1 (read as h2(-1) at t=0)
  {
    const int idx = w >> 1;                           // [0,128)
    st_u32_wt(&h2p[SLOT + idx*1024 + (cb*128 + (tid & 127))*4 + (tid >> 7)], 0u);
  }

  gridbar_g(gbar, 1);

  // ---------------- prologue: h1(0), c-state init ----------------
  float c1, c2 = 0.0f;
  {
    const float xv0 = xT[bcol];
    const float gi = fast_sigmoid(fmaf(xv0, wih1r[0], b1r[0]));
    const float gg = fast_tanh   (fmaf(xv0, wih1r[2], b1r[2]));
    const float go = fast_sigmoid(fmaf(xv0, wih1r[3], b1r[3]));
    c1 = gi * gg;
    const float hv = go * fast_tanh(c1);
    st_u32_wt(&h1p[p*1024 + bcol*4 + quad], pack_hl(hv));  // slot 0, [k>>2][b][k&3]
  }
  gridbar_g(gbar, 2);

  // ---------------- main loop: phase t computes h2(t), h1(t+1), out(t-1) ----------------
  for (int t = 0; t < TT; ++t){
    const int sR1 = ( t    & 1)*SLOT;     // h1(t)      (read)
    const int sR2 = ((t+1) & 1)*SLOT;     // h2(t-1)    (read)
    const int sW1 = ((t+1) & 1)*SLOT;     // h1(t+1)    (write)
    const int sW2 = ( t    & 1)*SLOT;     // h2(t)      (write)

    // out(t-1) partial: thread tid covers k = tid, batch row b_out
    float opart = unpack_f(h2p[sR2 + (tid>>2)*1024 + b_out*4 + (tid&3)]) * wlin_s[tid];

    f32x4 aA2 = {0,0,0,0}, aB2 = {0,0,0,0}, aA1 = {0,0,0,0}, aB1 = {0,0,0,0};
    const u32* q1 = h1p + sR1 + bcol*4 + quad*2048;
    const u32* q2 = h2p + sR2 + bcol*4 + quad*2048;

    // ---- h1(t) chunks: feed both the L2 tile and the L1 tile ----
    #pragma unroll
    for (int c = 0; c < 16; ++c){
      f16x8 bh, bl;
      build_frag4(q1 + c*8192, bh, bl);
      const f16x8 a2h = A2hi[c*64 + l];
      const f16x8 a2l = A2lo[c*64 + l];
      const f16x8 a1h = A1hi[c*64 + l];
      const f16x8 a1l = A1lo[c*64 + l];
      aA2 = mf(a2h, bh, aA2);
      aB2 = mf(a2h, bl, aB2);
      aB2 = mf(a2l, bh, aB2);
      aA1 = mf(a1h, bh, aA1);
      aB1 = mf(a1h, bl, aB1);
      aB1 = mf(a1l, bh, aB1);
    }
    // ---- h2(t-1) chunks: L2 tile only ----
    #pragma unroll
    for (int c = 0; c < 16; ++c){
      f16x8 bh, bl;
      build_frag4(q2 + c*8192, bh, bl);
      const f16x8 a2h = A2hi[(c+16)*64 + l];
      const f16x8 a2l = A2lo[(c+16)*64 + l];
      aA2 = mf(a2h, bh, aA2);
      aB2 = mf(a2h, bl, aB2);
      aB2 = mf(a2l, bh, aB2);
    }

    float* xw = &xch[wv][0];
    // ---- layer-2 cell (lane -> jj=quad, b=bcol after exchange) ----
    {
      f32x4 pre;
      #pragma unroll
      for (int i = 0; i < 4; ++i) pre[i] = fmaf(aB2[i], 1.0f/2048.0f, aA2[i]);
      *(f32x4*)&xw[lc*PADX + quad*4] = pre;          // [col][row], padded
      __threadfence_block();
      const float g0 = xw[lc*PADX + 0*4 + quad];
      const float g1 = xw[lc*PADX + 1*4 + quad];
      const float g2 = xw[lc*PADX + 2*4 + quad];
      const float g3 = xw[lc*PADX + 3*4 + quad];
      const float gi = fast_sigmoid(g0 + b2r[0]);
      const float gf = fast_sigmoid(g1 + b2r[1]);
      const float gg = fast_tanh   (g2 + b2r[2]);
      const float go = fast_sigmoid(g3 + b2r[3]);
      c2 = fmaf(gf, c2, gi*gg);
      const float hv = go * fast_tanh(c2);
      st_u32_wt(&h2p[sW2 + p*1024 + bcol*4 + quad], pack_hl(hv));
    }
    // ---- layer-1 cell (for t+1) ----
    {
      f32x4 pre;
      #pragma unroll
      for (int i = 0; i < 4; ++i) pre[i] = fmaf(aB1[i], 1.0f/2048.0f, aA1[i]);
      __threadfence_block();                          // prior reads done before overwrite
      *(f32x4*)&xw[lc*PADX + quad*4] = pre;
      __threadfence_block();
      const float g0 = xw[lc*PADX + 0*4 + quad];
      const float g1 = xw[lc*PADX + 1*4 + quad];
      const float g2 = xw[lc*PADX + 2*4 + quad];
      const float g3 = xw[lc*PADX + 3*4 + quad];
      const int tx = (t+1 < TT) ? (t+1) : (TT-1);
      const float xv = xT[(size_t)tx*BB + bcol];
      const float gi = fast_sigmoid(g0 + fmaf(xv, wih1r[0], b1r[0]));
      const float gf = fast_sigmoid(g1 + fmaf(xv, wih1r[1], b1r[1]));
      const float gg = fast_tanh   (g2 + fmaf(xv, wih1r[2], b1r[2]));
      const float go = fast_sigmoid(g3 + fmaf(xv, wih1r[3], b1r[3]));
      c1 = fmaf(gf, c1, gi*gg);
      const float hv = go * fast_tanh(c1);
      st_u32_wt(&h1p[sW1 + p*1024 + bcol*4 + quad], pack_hl(hv));
    }
    // ---- out(t-1) reduce (writes land pre-syncthreads) ----
    #pragma unroll
    for (int off = 32; off > 0; off >>= 1) opart += __shfl_down(opart, off, 64);
    if (l == 0) outpart[t & 1][wv] = opart;

    // ---- barrier: sync -> arrive -> (tid0: store out, overlapping) -> poll -> inv ----
    __syncthreads();
    if (tid == 0){
      __builtin_amdgcn_fence(__ATOMIC_RELEASE, "workgroup");
      const unsigned g = (blockIdx.x >> 1) & 15u;
      const unsigned ph = 1 + (unsigned)t;
      unsigned old = __hip_atomic_fetch_add(&dbar[g*16], 1u, __ATOMIC_RELAXED, __HIP_MEMORY_SCOPE_AGENT);
      if (old + 1u == 8u*ph){
        unsigned om = __hip_atomic_fetch_add(&dbar[256], 1u, __ATOMIC_RELAXED, __HIP_MEMORY_SCOPE_AGENT);
        if (om + 1u == 16u*ph){
          #pragma unroll
          for (int r = 0; r < 16; ++r)
            __hip_atomic_store(&dbar[320 + r*16], ph, __ATOMIC_RELAXED, __HIP_MEMORY_SCOPE_AGENT);
        }
      }
      if (t > 0){                                    // overlap with other WGs' arrival
        float s = blin;
        #pragma unroll
        for (int q2i = 0; q2i < 8; ++q2i) s += outpart[t & 1][q2i];
        st_f32_wt(&out[(size_t)b_out*TT + (t-1)], s);
      }
    }
    if ((tid & 63) == 0){                            // each wave polls independently
      const unsigned g = (blockIdx.x >> 1) & 15u;
      const unsigned ph = 1 + (unsigned)t;
      while (__hip_atomic_load(&dbar[320 + g*16], __ATOMIC_RELAXED, __HIP_MEMORY_SCOPE_AGENT) < ph){
        __builtin_amdgcn_s_sleep(1);
      }
    }
    __builtin_amdgcn_fence(__ATOMIC_ACQUIRE, "agent");
  }

  // ---------------- tail: out(1023) ----------------
  {
    float opart = unpack_f(h2p[((TT-1)&1)*SLOT + (tid>>2)*1024 + b_out*4 + (tid&3)]) * wlin_s[tid];
    #pragma unroll
    for (int off = 32; off > 0; off >>= 1) opart += __shfl_down(opart, off, 64);
    if (l == 0) outpart[0][wv] = opart;
    __syncthreads();
    if (tid == 0){
      float s = blin;
      #pragma unroll
      for (int q2i = 0; q2i < 8; ++q2i) s += outpart[0][q2i];
      st_f32_wt(&out[(size_t)b_out*TT + (TT-1)], s);
    }
  }
}

extern "C" void kernel_launch(void* const* d_in, const int* in_sizes, int n_in,
                              void* d_out, int out_size, void* d_ws, size_t ws_size,
                              hipStream_t stream) {
  const float* x     = (const float*)d_in[0];
  const float* W_ih1 = (const float*)d_in[1];
  const float* W_hh1 = (const float*)d_in[2];
  const float* b1    = (const float*)d_in[3];
  const float* W_ih2 = (const float*)d_in[4];
  const float* W_hh2 = (const float*)d_in[5];
  const float* b2    = (const float*)d_in[6];
  const float* W_lin = (const float*)d_in[7];
  const float* b_lin = (const float*)d_in[8];
  float* out = (float*)d_out;
  char* wsb  = (char*)d_ws;

  // zero the barrier region (ws is re-poisoned to 0xAA before every launch)
  hipMemsetAsync(d_ws, 0, 16384, stream);

  hipLaunchKernelGGL(lstm_mfma, dim3(NWG), dim3(NTHR), 0, stream,
                     x, W_ih1, W_hh1, b1, W_ih2, W_hh2, b2, W_lin, b_lin, out, wsb);
}

// Round 9
// 13449.118 us; speedup vs baseline: 1.9270x; 1.9270x over previous
//
#include <hip/hip_runtime.h>
#include <math.h>

// Problem constants
#define BB   256    // batch
#define TT   1024   // timesteps
#define HH   512    // hidden
#define NWG  256    // 1 WG per CU
#define NTHR 512    // 8 waves
#define SLOT (HH*BB)   // elements per h slot; hi-plane u16 + lo-plane u8 (e5m2)
#define PADX 20     // xch row stride (floats): conflict-free (verified: 10x conflict drop)

typedef _Float16 f16;
typedef _Float16 f16x8 __attribute__((ext_vector_type(8)));
typedef float    f32x4 __attribute__((ext_vector_type(4)));
typedef unsigned int u32;
typedef u32 u32x2 __attribute__((ext_vector_type(2)));
typedef unsigned short u16;
typedef unsigned char u8;

__device__ __forceinline__ f32x4 mf(f16x8 a, f16x8 b, f32x4 c){
  return __builtin_amdgcn_mfma_f32_16x16x32_f16(a, b, c, 0, 0, 0);
}

__device__ __forceinline__ float fast_sigmoid(float v){
  float e = __expf(-v);
  return __builtin_amdgcn_rcpf(1.0f + e);
}
__device__ __forceinline__ float fast_tanh(float v){
  float a = fabsf(v);
  float e = __expf(-2.0f * a);
  float r = (1.0f - e) * __builtin_amdgcn_rcpf(1.0f + e);
  return copysignf(r, v);
}

// split h -> hi f16 bits + lo e5m2 byte (lo = (h-hi)*2048, RN via +0x80 before truncate;
// e5m2 == f16 with low 8 mantissa bits dropped, so e5m2->f16 is exactly <<8)
__device__ __forceinline__ void split_h(float hv, u16& hb, u8& lb){
  const f16 hh = (f16)hv;
  const f16 lh = (f16)((hv - (float)hh) * 2048.0f);
  union {f16 f; u16 u;} ch, cl; ch.f = hh; cl.f = lh;
  hb = ch.u;
  lb = (u8)(((u32)cl.u + 0x80u) >> 8);
}
__device__ __forceinline__ float join_h(u16 hb, u8 lb){
  union {u16 u; f16 f;} h, l;
  h.u = hb; l.u = (u16)((u32)lb << 8);
  return (float)h.f + (float)l.f * (1.0f/2048.0f);
}
// device-coherent write-through stores (land at L3; L2 never dirty for these)
__device__ __forceinline__ void st_wt_u16(u16* p, u16 v){
  __hip_atomic_store(p, v, __ATOMIC_RELAXED, __HIP_MEMORY_SCOPE_AGENT);
}
__device__ __forceinline__ void st_wt_u8(u8* p, u8 v){
  __hip_atomic_store(p, v, __ATOMIC_RELAXED, __HIP_MEMORY_SCOPE_AGENT);
}
__device__ __forceinline__ void st_wt_f32(float* p, float v){
  __hip_atomic_store(p, v, __ATOMIC_RELAXED, __HIP_MEMORY_SCOPE_AGENT);
}

// build hi/lo f16x8 fragments: hi = 2x dwordx2 (k-order, no perms),
// lo = 2x dword e5m2 expanded by byte-perm (<<8).
__device__ __forceinline__ void build_hl(const u16* ph_, const u8* pl_, f16x8& fh, f16x8& fl){
  union {u32x2 d; u32 u[2];} ha, hb2;
  ha.d  = *(const u32x2*)ph_;            // k0..k3
  hb2.d = *(const u32x2*)(ph_ + 1024);   // k4..k7 (next k-group, stride 1024 u16)
  const u32 l0 = *(const u32*)pl_;
  const u32 l1 = *(const u32*)(pl_ + 1024);
  union {u32 u[4]; f16x8 f;} H, L;
  H.u[0]=ha.u[0]; H.u[1]=ha.u[1]; H.u[2]=hb2.u[0]; H.u[3]=hb2.u[1];
  L.u[0] = __builtin_amdgcn_perm(l0, 0u, 0x05010400u);   // [l0b1<<8 | l0b0<<8]
  L.u[1] = __builtin_amdgcn_perm(l0, 0u, 0x07010600u);
  L.u[2] = __builtin_amdgcn_perm(l1, 0u, 0x05010400u);
  L.u[3] = __builtin_amdgcn_perm(l1, 0u, 0x07010600u);
  fh = H.f; fl = L.f;
}

// GLOBAL fenced barrier (init only): all 256 WGs.
__device__ __forceinline__ void gridbar_g(unsigned* barb, unsigned ph){
  __syncthreads();
  if (threadIdx.x == 0){
    __builtin_amdgcn_fence(__ATOMIC_RELEASE, "agent");
    const unsigned g = blockIdx.x & 31u;
    unsigned old = __hip_atomic_fetch_add(&barb[g*16], 1u, __ATOMIC_RELAXED, __HIP_MEMORY_SCOPE_AGENT);
    if (old + 1u == 8u*ph){
      unsigned om = __hip_atomic_fetch_add(&barb[512], 1u, __ATOMIC_RELAXED, __HIP_MEMORY_SCOPE_AGENT);
      if (om + 1u == 32u*ph){
        #pragma unroll
        for (int r = 0; r < 32; ++r)
          __hip_atomic_store(&barb[544 + r*16], ph, __ATOMIC_RELAXED, __HIP_MEMORY_SCOPE_AGENT);
      }
    }
    while (__hip_atomic_load(&barb[544 + g*16], __ATOMIC_RELAXED, __HIP_MEMORY_SCOPE_AGENT) < ph){
      __builtin_amdgcn_s_sleep(2);
    }
    __builtin_amdgcn_fence(__ATOMIC_ACQUIRE, "agent");
  }
  __syncthreads();
}

// ws layout (bytes): [0,16K) barriers (dom0 @0, dom1 @4K, global @8K),
// [16K,16K+1M) xT fp32 [T][B], then h planes (2 slots each):
// h1h u16[2*SLOT], h1l u8[2*SLOT], h2h u16[2*SLOT], h2l u8[2*SLOT]  (1.5 MB total)
__global__ __launch_bounds__(NTHR, 2) void lstm_mfma(
    const float* __restrict__ x,      const float* __restrict__ W_ih1,
    const float* __restrict__ W_hh1,  const float* __restrict__ b1,
    const float* __restrict__ W_ih2,  const float* __restrict__ W_hh2,
    const float* __restrict__ b2,     const float* __restrict__ W_lin,
    const float* __restrict__ b_lin,  float* __restrict__ out,
    char* __restrict__ wsb)
{
  __shared__ f16x8 A2hi[2048], A2lo[2048], A1hi[1024], A1lo[1024]; // 96 KB
  __shared__ float xch[8][16*PADX];  // per-wave gate-exchange scratch (padded)
  __shared__ float wlin_s[512];
  __shared__ float outpart[2][8];

  unsigned* bar = (unsigned*)wsb;
  float* xT = (float*)(wsb + 16384);
  u16* h1h = (u16*)(wsb + 16384 + 1048576);
  u8*  h1l = (u8*) ((char*)h1h + 4*SLOT);
  u16* h2h = (u16*)((char*)h1l + 2*SLOT);
  u8*  h2l = (u8*) ((char*)h2h + 4*SLOT);

  const int w   = blockIdx.x,  tid = threadIdx.x;
  const int l   = tid & 63,    wv  = tid >> 6;       // lane, wave
  const int quad = l >> 4,     lc  = l & 15;
  const int p = w >> 1, cb = w & 1;                  // row-group, batch half (cb == XCD parity)
  const int j0 = 4*p;                                // this WG's 4 hidden columns
  const int bcol = cb*128 + wv*16 + lc;              // this lane's batch column
  const int jq = j0 + quad;                          // this lane's j (post-exchange)
  const int b_out = cb*128 + p;                      // out row handled by this WG (intra-half)
  unsigned* dbar = bar + cb*1024;                    // domain barrier base
  unsigned* gbar = bar + 2048;                       // global barrier base

  // ---------------- init: weight split into LDS frag-order ----------------
  {
    const int g_ = lc >> 2, jj_ = lc & 3;            // A-row m = lc -> (gate, jj)
    const int wrow = g_*HH + j0 + jj_;
    const float* rowI  = W_ih2 + (size_t)wrow*HH;
    const float* rowH2 = W_hh2 + (size_t)wrow*HH;
    const float* rowH1 = W_hh1 + (size_t)wrow*HH;
    for (int c = wv; c < 32; c += 8){
      const int kb = c*32 + quad*8;
      union {f16x8 v; f16 e[8];} hi8, lo8;
      #pragma unroll
      for (int i = 0; i < 8; ++i){
        const int k = kb + i;
        const float wval = (k < HH) ? rowI[k] : rowH2[k - HH];
        const f16 h_ = (f16)wval;
        hi8.e[i] = h_;
        lo8.e[i] = (f16)((wval - (float)h_) * 2048.0f);
      }
      A2hi[c*64 + l] = hi8.v;
      A2lo[c*64 + l] = lo8.v;
    }
    for (int c = wv; c < 16; c += 8){
      const int kb = c*32 + quad*8;
      union {f16x8 v; f16 e[8];} hi8, lo8;
      #pragma unroll
      for (int i = 0; i < 8; ++i){
        const float wval = rowH1[kb + i];
        const f16 h_ = (f16)wval;
        hi8.e[i] = h_;
        lo8.e[i] = (f16)((wval - (float)h_) * 2048.0f);
      }
      A1hi[c*64 + l] = hi8.v;
      A1lo[c*64 + l] = lo8.v;
    }
  }
  // per-lane scalars (j = jq)
  float wih1r[4], b1r[4], b2r[4];
  #pragma unroll
  for (int g = 0; g < 4; ++g){
    wih1r[g] = W_ih1[g*HH + jq];
    b1r[g]   = b1[g*HH + jq];
    b2r[g]   = b2[g*HH + jq];
  }
  const float blin = b_lin[0];
  wlin_s[tid] = W_lin[tid];

  // x transpose -> xT[t][b] (plain stores; made visible by the fenced global barrier)
  {
    const int gid = w*NTHR + tid;
    #pragma unroll
    for (int i2 = 0; i2 < 2; ++i2){
      const int idx = gid + i2*131072;
      const int bb2 = idx >> 10, tt2 = idx & (TT-1);
      xT[(size_t)tt2*BB + bb2] = x[idx];
    }
  }
  // zero h2 slot 1 (read as h2(-1) at t=0)
  {
    const int idx = w >> 1;                           // [0,128)
    const int off = SLOT + idx*1024 + (cb*128 + (tid & 127))*4 + (tid >> 7);
    st_wt_u16(&h2h[off], (u16)0);
    st_wt_u8 (&h2l[off], (u8)0);
  }

  gridbar_g(gbar, 1);

  // ---------------- prologue: h1(0), c-state init ----------------
  float c1, c2 = 0.0f;
  {
    const float xv0 = xT[bcol];
    const float gi = fast_sigmoid(fmaf(xv0, wih1r[0], b1r[0]));
    const float gg = fast_tanh   (fmaf(xv0, wih1r[2], b1r[2]));
    const float go = fast_sigmoid(fmaf(xv0, wih1r[3], b1r[3]));
    c1 = gi * gg;
    const float hv = go * fast_tanh(c1);
    u16 hb; u8 lb; split_h(hv, hb, lb);
    const int off = p*1024 + bcol*4 + quad;           // slot 0, [k>>2][b][k&3]
    st_wt_u16(&h1h[off], hb);
    st_wt_u8 (&h1l[off], lb);
  }
  gridbar_g(gbar, 2);

  // ---------------- main loop: phase t computes h2(t), h1(t+1), out(t-1) ----------------
  for (int t = 0; t < TT; ++t){
    const int sR1 = ( t    & 1)*SLOT;     // h1(t)      (read)
    const int sR2 = ((t+1) & 1)*SLOT;     // h2(t-1)    (read)
    const int sW1 = ((t+1) & 1)*SLOT;     // h1(t+1)    (write)
    const int sW2 = ( t    & 1)*SLOT;     // h2(t)      (write)

    // out(t-1) partial: thread tid covers k = tid, batch row b_out
    const int oidx = sR2 + (tid>>2)*1024 + b_out*4 + (tid&3);
    float opart = join_h(h2h[oidx], h2l[oidx]) * wlin_s[tid];

    f32x4 aA2 = {0,0,0,0}, aB2 = {0,0,0,0}, aA1 = {0,0,0,0}, aB1 = {0,0,0,0};
    const u16* q1h = h1h + sR1 + quad*2048 + bcol*4;
    const u8*  q1l = h1l + sR1 + quad*2048 + bcol*4;
    const u16* q2h = h2h + sR2 + quad*2048 + bcol*4;
    const u8*  q2l = h2l + sR2 + quad*2048 + bcol*4;

    // ---- h1(t) chunks: feed both the L2 tile and the L1 tile ----
    #pragma unroll
    for (int c = 0; c < 16; ++c){
      f16x8 bh, bl;
      build_hl(q1h + c*8192, q1l + c*8192, bh, bl);
      const f16x8 a2h = A2hi[c*64 + l];
      const f16x8 a2l = A2lo[c*64 + l];
      const f16x8 a1h = A1hi[c*64 + l];
      const f16x8 a1l = A1lo[c*64 + l];
      aA2 = mf(a2h, bh, aA2);
      aB2 = mf(a2h, bl, aB2);
      aB2 = mf(a2l, bh, aB2);
      aA1 = mf(a1h, bh, aA1);
      aB1 = mf(a1h, bl, aB1);
      aB1 = mf(a1l, bh, aB1);
    }
    // ---- h2(t-1) chunks: L2 tile only ----
    #pragma unroll
    for (int c = 0; c < 16; ++c){
      f16x8 bh, bl;
      build_hl(q2h + c*8192, q2l + c*8192, bh, bl);
      const f16x8 a2h = A2hi[(c+16)*64 + l];
      const f16x8 a2l = A2lo[(c+16)*64 + l];
      aA2 = mf(a2h, bh, aA2);
      aB2 = mf(a2h, bl, aB2);
      aB2 = mf(a2l, bh, aB2);
    }

    float* xw = &xch[wv][0];
    // ---- layer-2 cell (lane -> jj=quad, b=bcol after exchange) ----
    {
      f32x4 pre;
      #pragma unroll
      for (int i = 0; i < 4; ++i) pre[i] = fmaf(aB2[i], 1.0f/2048.0f, aA2[i]);
      *(f32x4*)&xw[lc*PADX + quad*4] = pre;          // [col][row], padded
      __threadfence_block();
      const float g0 = xw[lc*PADX + 0*4 + quad];
      const float g1 = xw[lc*PADX + 1*4 + quad];
      const float g2 = xw[lc*PADX + 2*4 + quad];
      const float g3 = xw[lc*PADX + 3*4 + quad];
      const float gi = fast_sigmoid(g0 + b2r[0]);
      const float gf = fast_sigmoid(g1 + b2r[1]);
      const float gg = fast_tanh   (g2 + b2r[2]);
      const float go = fast_sigmoid(g3 + b2r[3]);
      c2 = fmaf(gf, c2, gi*gg);
      const float hv = go * fast_tanh(c2);
      u16 hb; u8 lb; split_h(hv, hb, lb);
      const int off = sW2 + p*1024 + bcol*4 + quad;
      st_wt_u16(&h2h[off], hb);
      st_wt_u8 (&h2l[off], lb);
    }
    // ---- layer-1 cell (for t+1) ----
    {
      f32x4 pre;
      #pragma unroll
      for (int i = 0; i < 4; ++i) pre[i] = fmaf(aB1[i], 1.0f/2048.0f, aA1[i]);
      __threadfence_block();                          // prior reads done before overwrite
      *(f32x4*)&xw[lc*PADX + quad*4] = pre;
      __threadfence_block();
      const float g0 = xw[lc*PADX + 0*4 + quad];
      const float g1 = xw[lc*PADX + 1*4 + quad];
      const float g2 = xw[lc*PADX + 2*4 + quad];
      const float g3 = xw[lc*PADX + 3*4 + quad];
      const int tx = (t+1 < TT) ? (t+1) : (TT-1);
      const float xv = xT[(size_t)tx*BB + bcol];
      const float gi = fast_sigmoid(g0 + fmaf(xv, wih1r[0], b1r[0]));
      const float gf = fast_sigmoid(g1 + fmaf(xv, wih1r[1], b1r[1]));
      const float gg = fast_tanh   (g2 + fmaf(xv, wih1r[2], b1r[2]));
      const float go = fast_sigmoid(g3 + fmaf(xv, wih1r[3], b1r[3]));
      c1 = fmaf(gf, c1, gi*gg);
      const float hv = go * fast_tanh(c1);
      u16 hb; u8 lb; split_h(hv, hb, lb);
      const int off = sW1 + p*1024 + bcol*4 + quad;
      st_wt_u16(&h1h[off], hb);
      st_wt_u8 (&h1l[off], lb);
    }
    // ---- out(t-1) reduce (lands pre-syncthreads) ----
    #pragma unroll
    for (int off = 32; off > 0; off >>= 1) opart += __shfl_down(opart, off, 64);
    if (l == 0) outpart[t & 1][wv] = opart;

    // ---- domain barrier: sync -> tid0 {wg-release, arrive, out-store, poll, ONE agent-acquire} -> sync
    __syncthreads();                                   // drains WT stores (vmcnt 0)
    if (tid == 0){
      __builtin_amdgcn_fence(__ATOMIC_RELEASE, "workgroup");   // ordering only, no wbl2
      const unsigned g = (blockIdx.x >> 1) & 15u;
      const unsigned ph = 1 + (unsigned)t;
      unsigned old = __hip_atomic_fetch_add(&dbar[g*16], 1u, __ATOMIC_RELAXED, __HIP_MEMORY_SCOPE_AGENT);
      if (old + 1u == 8u*ph){
        unsigned om = __hip_atomic_fetch_add(&dbar[256], 1u, __ATOMIC_RELAXED, __HIP_MEMORY_SCOPE_AGENT);
        if (om + 1u == 16u*ph){
          #pragma unroll
          for (int r = 0; r < 16; ++r)
            __hip_atomic_store(&dbar[320 + r*16], ph, __ATOMIC_RELAXED, __HIP_MEMORY_SCOPE_AGENT);
        }
      }
      if (t > 0){                                     // overlap with other WGs' arrival
        float s = blin;
        #pragma unroll
        for (int q2i = 0; q2i < 8; ++q2i) s += outpart[t & 1][q2i];
        st_wt_f32(&out[(size_t)b_out*TT + (t-1)], s);
      }
      while (__hip_atomic_load(&dbar[320 + g*16], __ATOMIC_RELAXED, __HIP_MEMORY_SCOPE_AGENT) < ph){
        __builtin_amdgcn_s_sleep(1);
      }
      __builtin_amdgcn_fence(__ATOMIC_ACQUIRE, "agent");  // ONE buffer_inv per WG
    }
    __syncthreads();
  }

  // ---------------- tail: out(1023) ----------------
  {
    const int oidx = ((TT-1)&1)*SLOT + (tid>>2)*1024 + b_out*4 + (tid&3);
    float opart = join_h(h2h[oidx], h2l[oidx]) * wlin_s[tid];
    #pragma unroll
    for (int off = 32; off > 0; off >>= 1) opart += __shfl_down(opart, off, 64);
    if (l == 0) outpart[0][wv] = opart;
    __syncthreads();
    if (tid == 0){
      float s = blin;
      #pragma unroll
      for (int q2i = 0; q2i < 8; ++q2i) s += outpart[0][q2i];
      st_wt_f32(&out[(size_t)b_out*TT + (TT-1)], s);
    }
  }
}

extern "C" void kernel_launch(void* const* d_in, const int* in_sizes, int n_in,
                              void* d_out, int out_size, void* d_ws, size_t ws_size,
                              hipStream_t stream) {
  const float* x     = (const float*)d_in[0];
  const float* W_ih1 = (const float*)d_in[1];
  const float* W_hh1 = (const float*)d_in[2];
  const float* b1    = (const float*)d_in[3];
  const float* W_ih2 = (const float*)d_in[4];
  const float* W_hh2 = (const float*)d_in[5];
  const float* b2    = (const float*)d_in[6];
  const float* W_lin = (const float*)d_in[7];
  const float* b_lin = (const float*)d_in[8];
  float* out = (float*)d_out;
  char* wsb  = (char*)d_ws;

  // zero the barrier region (ws is re-poisoned to 0xAA before every launch)
  hipMemsetAsync(d_ws, 0, 16384, stream);

  hipLaunchKernelGGL(lstm_mfma, dim3(NWG), dim3(NTHR), 0, stream,
                     x, W_ih1, W_hh1, b1, W_ih2, W_hh2, b2, W_lin, b_lin, out, wsb);
}

// Round 10
// 13118.834 us; speedup vs baseline: 1.9755x; 1.0252x over previous
//
#include <hip/hip_runtime.h>
#include <math.h>

// Problem constants
#define BB   256    // batch
#define TT   1024   // timesteps
#define HH   512    // hidden
#define NWG  256    // 1 WG per CU
#define NTHR 512    // 8 waves
#define SLOT (HH*BB)   // elements per h slot; hi-plane u16 + lo-plane u8 (e5m2)
#define PADX 20     // xch row stride (floats): conflict-free (verified: 10x conflict drop)

typedef _Float16 f16;
typedef _Float16 f16x8 __attribute__((ext_vector_type(8)));
typedef float    f32x4 __attribute__((ext_vector_type(4)));
typedef unsigned int u32;
typedef u32 u32x2 __attribute__((ext_vector_type(2)));
typedef unsigned short u16;
typedef unsigned char u8;

__device__ __forceinline__ f32x4 mf(f16x8 a, f16x8 b, f32x4 c){
  return __builtin_amdgcn_mfma_f32_16x16x32_f16(a, b, c, 0, 0, 0);
}

__device__ __forceinline__ float fast_sigmoid(float v){
  float e = __expf(-v);
  return __builtin_amdgcn_rcpf(1.0f + e);
}
__device__ __forceinline__ float fast_tanh(float v){
  float a = fabsf(v);
  float e = __expf(-2.0f * a);
  float r = (1.0f - e) * __builtin_amdgcn_rcpf(1.0f + e);
  return copysignf(r, v);
}

// split h -> hi f16 bits + lo e5m2 byte (lo = (h-hi)*2048, RN via +0x80 before truncate;
// e5m2 == f16 with low 8 mantissa bits dropped, so e5m2->f16 is exactly <<8)
__device__ __forceinline__ void split_h(float hv, u16& hb, u8& lb){
  const f16 hh = (f16)hv;
  const f16 lh = (f16)((hv - (float)hh) * 2048.0f);
  union {f16 f; u16 u;} ch, cl; ch.f = hh; cl.f = lh;
  hb = ch.u;
  lb = (u8)(((u32)cl.u + 0x80u) >> 8);
}
__device__ __forceinline__ float join_h(u16 hb, u8 lb){
  union {u16 u; f16 f;} h, l;
  h.u = hb; l.u = (u16)((u32)lb << 8);
  return (float)h.f + (float)l.f * (1.0f/2048.0f);
}
// device-coherent write-through stores (land at L3/HBM; L2 never dirty for these)
__device__ __forceinline__ void st_wt_u16(u16* p, u16 v){
  __hip_atomic_store(p, v, __ATOMIC_RELAXED, __HIP_MEMORY_SCOPE_AGENT);
}
__device__ __forceinline__ void st_wt_u8(u8* p, u8 v){
  __hip_atomic_store(p, v, __ATOMIC_RELAXED, __HIP_MEMORY_SCOPE_AGENT);
}
__device__ __forceinline__ void st_wt_f32(float* p, float v){
  __hip_atomic_store(p, v, __ATOMIC_RELAXED, __HIP_MEMORY_SCOPE_AGENT);
}

// build hi/lo f16x8 fragments: hi = 2x dwordx2 (k-order, no perms),
// lo = 2x dword e5m2 expanded by byte-perm (<<8).
__device__ __forceinline__ void build_hl(const u16* ph_, const u8* pl_, f16x8& fh, f16x8& fl){
  union {u32x2 d; u32 u[2];} ha, hb2;
  ha.d  = *(const u32x2*)ph_;            // k0..k3
  hb2.d = *(const u32x2*)(ph_ + 1024);   // k4..k7 (next k-group, stride 1024 u16)
  const u32 l0 = *(const u32*)pl_;
  const u32 l1 = *(const u32*)(pl_ + 1024);
  union {u32 u[4]; f16x8 f;} H, L;
  H.u[0]=ha.u[0]; H.u[1]=ha.u[1]; H.u[2]=hb2.u[0]; H.u[3]=hb2.u[1];
  L.u[0] = __builtin_amdgcn_perm(l0, 0u, 0x05010400u);   // [l0b1<<8 | l0b0<<8]
  L.u[1] = __builtin_amdgcn_perm(l0, 0u, 0x07010600u);
  L.u[2] = __builtin_amdgcn_perm(l1, 0u, 0x05010400u);
  L.u[3] = __builtin_amdgcn_perm(l1, 0u, 0x07010600u);
  fh = H.f; fl = L.f;
}

// GLOBAL fenced barrier (init only): all 256 WGs.
__device__ __forceinline__ void gridbar_g(unsigned* barb, unsigned ph){
  __syncthreads();
  if (threadIdx.x == 0){
    __builtin_amdgcn_fence(__ATOMIC_RELEASE, "agent");
    const unsigned g = blockIdx.x & 31u;
    unsigned old = __hip_atomic_fetch_add(&barb[g*16], 1u, __ATOMIC_RELAXED, __HIP_MEMORY_SCOPE_AGENT);
    if (old + 1u == 8u*ph){
      unsigned om = __hip_atomic_fetch_add(&barb[512], 1u, __ATOMIC_RELAXED, __HIP_MEMORY_SCOPE_AGENT);
      if (om + 1u == 32u*ph){
        #pragma unroll
        for (int r = 0; r < 32; ++r)
          __hip_atomic_store(&barb[544 + r*16], ph, __ATOMIC_RELAXED, __HIP_MEMORY_SCOPE_AGENT);
      }
    }
    while (__hip_atomic_load(&barb[544 + g*16], __ATOMIC_RELAXED, __HIP_MEMORY_SCOPE_AGENT) < ph){
      __builtin_amdgcn_s_sleep(2);
    }
    __builtin_amdgcn_fence(__ATOMIC_ACQUIRE, "agent");
  }
  __syncthreads();
}

// ws layout (bytes): [0,16K) barriers (dom0 @0, dom1 @4K, global @8K),
// [16K,16K+1M) xT fp32 [T][B], then h planes (2 slots each):
// h1h u16[2*SLOT], h1l u8[2*SLOT], h2h u16[2*SLOT], h2l u8[2*SLOT]  (1.5 MB total)
__global__ __launch_bounds__(NTHR, 2) void lstm_mfma(
    const float* __restrict__ x,      const float* __restrict__ W_ih1,
    const float* __restrict__ W_hh1,  const float* __restrict__ b1,
    const float* __restrict__ W_ih2,  const float* __restrict__ W_hh2,
    const float* __restrict__ b2,     const float* __restrict__ W_lin,
    const float* __restrict__ b_lin,  float* __restrict__ out,
    char* __restrict__ wsb)
{
  __shared__ f16x8 A2hi[2048], A2lo[2048], A1hi[1024], A1lo[1024]; // 96 KB
  __shared__ float xch[8][16*PADX];  // per-wave gate-exchange scratch (padded)
  __shared__ float wlin_s[512];
  __shared__ float outpart[2][8];

  unsigned* bar = (unsigned*)wsb;
  float* xT = (float*)(wsb + 16384);
  u16* h1h = (u16*)(wsb + 16384 + 1048576);
  u8*  h1l = (u8*) ((char*)h1h + 4*SLOT);
  u16* h2h = (u16*)((char*)h1l + 2*SLOT);
  u8*  h2l = (u8*) ((char*)h2h + 4*SLOT);

  const int w   = blockIdx.x,  tid = threadIdx.x;
  const int l   = tid & 63,    wv  = tid >> 6;       // lane, wave
  const int quad = l >> 4,     lc  = l & 15;
  const int p = w >> 1, cb = w & 1;                  // row-group, batch half (cb == XCD parity)
  const int j0 = 4*p;                                // this WG's 4 hidden columns
  const int bcol = cb*128 + wv*16 + lc;              // this lane's batch column
  const int jq = j0 + quad;                          // this lane's j (post-exchange)
  const int b_out = cb*128 + p;                      // out row handled by this WG (intra-half)
  unsigned* dbar = bar + cb*1024;                    // domain barrier base
  unsigned* gbar = bar + 2048;                       // global barrier base

  // ---------------- init: weight split into LDS frag-order ----------------
  {
    const int g_ = lc >> 2, jj_ = lc & 3;            // A-row m = lc -> (gate, jj)
    const int wrow = g_*HH + j0 + jj_;
    const float* rowI  = W_ih2 + (size_t)wrow*HH;
    const float* rowH2 = W_hh2 + (size_t)wrow*HH;
    const float* rowH1 = W_hh1 + (size_t)wrow*HH;
    for (int c = wv; c < 32; c += 8){
      const int kb = c*32 + quad*8;
      union {f16x8 v; f16 e[8];} hi8, lo8;
      #pragma unroll
      for (int i = 0; i < 8; ++i){
        const int k = kb + i;
        const float wval = (k < HH) ? rowI[k] : rowH2[k - HH];
        const f16 h_ = (f16)wval;
        hi8.e[i] = h_;
        lo8.e[i] = (f16)((wval - (float)h_) * 2048.0f);
      }
      A2hi[c*64 + l] = hi8.v;
      A2lo[c*64 + l] = lo8.v;
    }
    for (int c = wv; c < 16; c += 8){
      const int kb = c*32 + quad*8;
      union {f16x8 v; f16 e[8];} hi8, lo8;
      #pragma unroll
      for (int i = 0; i < 8; ++i){
        const float wval = rowH1[kb + i];
        const f16 h_ = (f16)wval;
        hi8.e[i] = h_;
        lo8.e[i] = (f16)((wval - (float)h_) * 2048.0f);
      }
      A1hi[c*64 + l] = hi8.v;
      A1lo[c*64 + l] = lo8.v;
    }
  }
  // per-lane scalars (j = jq)
  float wih1r[4], b1r[4], b2r[4];
  #pragma unroll
  for (int g = 0; g < 4; ++g){
    wih1r[g] = W_ih1[g*HH + jq];
    b1r[g]   = b1[g*HH + jq];
    b2r[g]   = b2[g*HH + jq];
  }
  const float blin = b_lin[0];
  wlin_s[tid] = W_lin[tid];

  // x transpose -> xT[t][b] (plain stores; made visible by the fenced global barrier)
  {
    const int gid = w*NTHR + tid;
    #pragma unroll
    for (int i2 = 0; i2 < 2; ++i2){
      const int idx = gid + i2*131072;
      const int bb2 = idx >> 10, tt2 = idx & (TT-1);
      xT[(size_t)tt2*BB + bb2] = x[idx];
    }
  }
  // zero h2 slot 1 (read as h2(-1) at t=0)
  {
    const int idx = w >> 1;                           // [0,128)
    const int off = SLOT + idx*1024 + (cb*128 + (tid & 127))*4 + (tid >> 7);
    st_wt_u16(&h2h[off], (u16)0);
    st_wt_u8 (&h2l[off], (u8)0);
  }

  gridbar_g(gbar, 1);

  // ---------------- prologue: h1(0), c-state init ----------------
  float c1, c2 = 0.0f;
  {
    const float xv0 = xT[bcol];
    const float gi = fast_sigmoid(fmaf(xv0, wih1r[0], b1r[0]));
    const float gg = fast_tanh   (fmaf(xv0, wih1r[2], b1r[2]));
    const float go = fast_sigmoid(fmaf(xv0, wih1r[3], b1r[3]));
    c1 = gi * gg;
    const float hv = go * fast_tanh(c1);
    u16 hb; u8 lb; split_h(hv, hb, lb);
    const int off = p*1024 + bcol*4 + quad;           // slot 0, [k>>2][b][k&3]
    st_wt_u16(&h1h[off], hb);
    st_wt_u8 (&h1l[off], lb);
  }
  gridbar_g(gbar, 2);

  // ---------------- main loop: phase t computes h2(t), h1(t+1), out(t-1) ----------------
  for (int t = 0; t < TT; ++t){
    const int sR1 = ( t    & 1)*SLOT;     // h1(t)      (read)
    const int sR2 = ((t+1) & 1)*SLOT;     // h2(t-1)    (read)
    const int sW1 = ((t+1) & 1)*SLOT;     // h1(t+1)    (write)
    const int sW2 = ( t    & 1)*SLOT;     // h2(t)      (write)

    // out(t-1) partial: thread tid covers k = tid, batch row b_out
    const int oidx = sR2 + (tid>>2)*1024 + b_out*4 + (tid&3);
    float opart = join_h(h2h[oidx], h2l[oidx]) * wlin_s[tid];

    f32x4 aA2 = {0,0,0,0}, aB2 = {0,0,0,0}, aA1 = {0,0,0,0}, aB1 = {0,0,0,0};
    const u16* q1h = h1h + sR1 + quad*2048 + bcol*4;
    const u8*  q1l = h1l + sR1 + quad*2048 + bcol*4;
    const u16* q2h = h2h + sR2 + quad*2048 + bcol*4;
    const u8*  q2l = h2l + sR2 + quad*2048 + bcol*4;

    // ---- h1(t) chunks: feed both the L2 tile and the L1 tile ----
    #pragma unroll
    for (int c = 0; c < 16; ++c){
      f16x8 bh, bl;
      build_hl(q1h + c*8192, q1l + c*8192, bh, bl);
      const f16x8 a2h = A2hi[c*64 + l];
      const f16x8 a2l = A2lo[c*64 + l];
      const f16x8 a1h = A1hi[c*64 + l];
      const f16x8 a1l = A1lo[c*64 + l];
      aA2 = mf(a2h, bh, aA2);
      aB2 = mf(a2h, bl, aB2);
      aB2 = mf(a2l, bh, aB2);
      aA1 = mf(a1h, bh, aA1);
      aB1 = mf(a1h, bl, aB1);
      aB1 = mf(a1l, bh, aB1);
    }
    // ---- h2(t-1) chunks: L2 tile only ----
    #pragma unroll
    for (int c = 0; c < 16; ++c){
      f16x8 bh, bl;
      build_hl(q2h + c*8192, q2l + c*8192, bh, bl);
      const f16x8 a2h = A2hi[(c+16)*64 + l];
      const f16x8 a2l = A2lo[(c+16)*64 + l];
      aA2 = mf(a2h, bh, aA2);
      aB2 = mf(a2h, bl, aB2);
      aB2 = mf(a2l, bh, aB2);
    }

    float* xw = &xch[wv][0];
    // ---- layer-2 cell (lane -> jj=quad, b=bcol after exchange) ----
    {
      f32x4 pre;
      #pragma unroll
      for (int i = 0; i < 4; ++i) pre[i] = fmaf(aB2[i], 1.0f/2048.0f, aA2[i]);
      *(f32x4*)&xw[lc*PADX + quad*4] = pre;          // [col][row], padded
      __threadfence_block();
      const float g0 = xw[lc*PADX + 0*4 + quad];
      const float g1 = xw[lc*PADX + 1*4 + quad];
      const float g2 = xw[lc*PADX + 2*4 + quad];
      const float g3 = xw[lc*PADX + 3*4 + quad];
      const float gi = fast_sigmoid(g0 + b2r[0]);
      const float gf = fast_sigmoid(g1 + b2r[1]);
      const float gg = fast_tanh   (g2 + b2r[2]);
      const float go = fast_sigmoid(g3 + b2r[3]);
      c2 = fmaf(gf, c2, gi*gg);
      const float hv = go * fast_tanh(c2);
      u16 hb; u8 lb; split_h(hv, hb, lb);
      const int off = sW2 + p*1024 + bcol*4 + quad;
      st_wt_u16(&h2h[off], hb);
      st_wt_u8 (&h2l[off], lb);
    }
    // ---- layer-1 cell (for t+1) ----
    {
      f32x4 pre;
      #pragma unroll
      for (int i = 0; i < 4; ++i) pre[i] = fmaf(aB1[i], 1.0f/2048.0f, aA1[i]);
      __threadfence_block();                          // prior reads done before overwrite
      *(f32x4*)&xw[lc*PADX + quad*4] = pre;
      __threadfence_block();
      const float g0 = xw[lc*PADX + 0*4 + quad];
      const float g1 = xw[lc*PADX + 1*4 + quad];
      const float g2 = xw[lc*PADX + 2*4 + quad];
      const float g3 = xw[lc*PADX + 3*4 + quad];
      const int tx = (t+1 < TT) ? (t+1) : (TT-1);
      const float xv = xT[(size_t)tx*BB + bcol];
      const float gi = fast_sigmoid(g0 + fmaf(xv, wih1r[0], b1r[0]));
      const float gf = fast_sigmoid(g1 + fmaf(xv, wih1r[1], b1r[1]));
      const float gg = fast_tanh   (g2 + fmaf(xv, wih1r[2], b1r[2]));
      const float go = fast_sigmoid(g3 + fmaf(xv, wih1r[3], b1r[3]));
      c1 = fmaf(gf, c1, gi*gg);
      const float hv = go * fast_tanh(c1);
      u16 hb; u8 lb; split_h(hv, hb, lb);
      const int off = sW1 + p*1024 + bcol*4 + quad;
      st_wt_u16(&h1h[off], hb);
      st_wt_u8 (&h1l[off], lb);
    }
    // ---- out(t-1) reduce (lands pre-syncthreads) ----
    #pragma unroll
    for (int off = 32; off > 0; off >>= 1) opart += __shfl_down(opart, off, 64);
    if (l == 0) outpart[t & 1][wv] = opart;

    // ---- domain barrier with EARLY L2-invalidate ----
    // Key change vs R9: the agent-acquire fence (buffer_inv) is issued at
    // ARRIVAL, not after the poll. No WG touches next-step slot addresses
    // between any inv and the flag release (those addresses were last read
    // 2 steps ago), so all invs complete before any consumer fill -> the
    // 32 WGs of an XCD share one clean L2 refill instead of wiping each
    // other's fills 32x per step.
    __syncthreads();                                   // drains WT stores (vmcnt 0)
    if (tid == 0){
      __builtin_amdgcn_fence(__ATOMIC_RELEASE, "workgroup");   // ordering only, no wbl2
      const unsigned g = (blockIdx.x >> 1) & 15u;
      const unsigned ph = 1 + (unsigned)t;
      unsigned old = __hip_atomic_fetch_add(&dbar[g*16], 1u, __ATOMIC_RELAXED, __HIP_MEMORY_SCOPE_AGENT);
      if (old + 1u == 8u*ph){
        unsigned om = __hip_atomic_fetch_add(&dbar[256], 1u, __ATOMIC_RELAXED, __HIP_MEMORY_SCOPE_AGENT);
        if (om + 1u == 16u*ph){
          #pragma unroll
          for (int r = 0; r < 16; ++r)
            __hip_atomic_store(&dbar[320 + r*16], ph, __ATOMIC_RELAXED, __HIP_MEMORY_SCOPE_AGENT);
        }
      }
      __builtin_amdgcn_fence(__ATOMIC_ACQUIRE, "agent");  // EARLY buffer_inv, off critical path
      if (t > 0){                                     // overlap with other WGs' arrival
        float s = blin;
        #pragma unroll
        for (int q2i = 0; q2i < 8; ++q2i) s += outpart[t & 1][q2i];
        st_wt_f32(&out[(size_t)b_out*TT + (t-1)], s);
      }
      while (__hip_atomic_load(&dbar[320 + g*16], __ATOMIC_RELAXED, __HIP_MEMORY_SCOPE_AGENT) < ph){
        __builtin_amdgcn_s_sleep(1);
      }
      asm volatile("" ::: "memory");                  // compiler-only ordering after poll
    }
    __syncthreads();
  }

  // ---------------- tail: out(1023) ----------------
  {
    const int oidx = ((TT-1)&1)*SLOT + (tid>>2)*1024 + b_out*4 + (tid&3);
    float opart = join_h(h2h[oidx], h2l[oidx]) * wlin_s[tid];
    #pragma unroll
    for (int off = 32; off > 0; off >>= 1) opart += __shfl_down(opart, off, 64);
    if (l == 0) outpart[0][wv] = opart;
    __syncthreads();
    if (tid == 0){
      float s = blin;
      #pragma unroll
      for (int q2i = 0; q2i < 8; ++q2i) s += outpart[0][q2i];
      st_wt_f32(&out[(size_t)b_out*TT + (TT-1)], s);
    }
  }
}

extern "C" void kernel_launch(void* const* d_in, const int* in_sizes, int n_in,
                              void* d_out, int out_size, void* d_ws, size_t ws_size,
                              hipStream_t stream) {
  const float* x     = (const float*)d_in[0];
  const float* W_ih1 = (const float*)d_in[1];
  const float* W_hh1 = (const float*)d_in[2];
  const float* b1    = (const float*)d_in[3];
  const float* W_ih2 = (const float*)d_in[4];
  const float* W_hh2 = (const float*)d_in[5];
  const float* b2    = (const float*)d_in[6];
  const float* W_lin = (const float*)d_in[7];
  const float* b_lin = (const float*)d_in[8];
  float* out = (float*)d_out;
  char* wsb  = (char*)d_ws;

  // zero the barrier region (ws is re-poisoned to 0xAA before every launch)
  hipMemsetAsync(d_ws, 0, 16384, stream);

  hipLaunchKernelGGL(lstm_mfma, dim3(NWG), dim3(NTHR), 0, stream,
                     x, W_ih1, W_hh1, b1, W_ih2, W_hh2, b2, W_lin, b_lin, out, wsb);
}